// Round 1
// baseline (17937.779 us; speedup 1.0000x reference)
//
#include <hip/hip_runtime.h>
#include <hip/hip_bf16.h>

typedef __attribute__((ext_vector_type(8))) short bf16x8;
typedef __attribute__((ext_vector_type(4))) float f32x4;

#define MFMA16(a,b,c) __builtin_amdgcn_mfma_f32_16x16x32_bf16((a),(b),(c),0,0,0)

// ---------------- workspace layout (byte offsets) ----------------
static constexpr long OFF_WT  = 0;           // bf16 transposed weights, 46,137,344 B
static constexpr long OFF_H16 = 46137344;    // h bf16 [2 parity][4 unit][64*1024] = 1,048,576 B
static constexpr long OFF_Y0R = 47185920;    // y0 ring bf16 [2 slot][2 dir][65536] = 524,288 B
static constexpr long OFF_Y1R = 47710208;    // y1 ring bf16 = 524,288 B
static constexpr long OFF_BAR = 48234496;    // barrier: 8 group cnts @ +g*128, top @ +1024, gen @ +1152
// end = 48,236,544 B  (< 48 MiB, the budget proven by the previous kernel)

// element offsets (bf16) within weight region (unchanged from previous kernel)
static constexpr long E_FW_WXT0 = 0;         // [3072][512]
static constexpr long E_FW_WHT0 = 1572864;   // [3072][1024]
static constexpr long E_FW_WXT1 = 4718592;
static constexpr long E_FW_WHT1 = 7864320;
static constexpr long E_BW_WXT0 = 11010048;
static constexpr long E_BW_WHT0 = 12582912;
static constexpr long E_BW_WXT1 = 15728640;
static constexpr long E_BW_WHT1 = 18874368;
static constexpr long E_FCWT    = 22020096;  // [512][2048]

static constexpr long OUT_FWH = 16777216;    // fw_h [2][64][1024] in d_out (float offsets)
static constexpr long OUT_BWH = 16908288;

__device__ __forceinline__ float sig_(float x) {
  x = fminf(fmaxf(x, -30.f), 30.f);
  return 1.f / (1.f + __expf(-x));
}
__device__ __forceinline__ float tanh_(float x) {
  x = fminf(fmaxf(x, -15.f), 15.f);
  float e = __expf(2.f * x);
  return (e - 1.f) / (e + 1.f);
}
__device__ __forceinline__ bf16x8 bc8(uint4 v) { return __builtin_bit_cast(bf16x8, v); }
__device__ __forceinline__ unsigned f2bfu(float f) {
  __hip_bfloat16 h = __float2bfloat16(f);
  return (unsigned)*(unsigned short*)&h;
}
// 8 fp32 (two uint4-of-float4) -> 8 packed bf16 (one uint4); same packing as old cvt8
__device__ __forceinline__ uint4 cvt8v(uint4 u0, uint4 u1) {
  float4 a = __builtin_bit_cast(float4, u0);
  float4 b = __builtin_bit_cast(float4, u1);
  uint4 r;
  r.x = f2bfu(a.x) | (f2bfu(a.y) << 16);
  r.y = f2bfu(a.z) | (f2bfu(a.w) << 16);
  r.z = f2bfu(b.x) | (f2bfu(b.y) << 16);
  r.w = f2bfu(b.z) | (f2bfu(b.w) << 16);
  return r;
}

// ---------------- transpose+cast: src f32 [R][C] -> dst bf16 [C][R] ----------------
__global__ void transpose_cast(const float* __restrict__ src, __hip_bfloat16* __restrict__ dst,
                               int R, int C) {
  __shared__ float tile[32][33];
  int tx = threadIdx.x, ty = threadIdx.y;
  int c0 = blockIdx.x * 32, r0 = blockIdx.y * 32;
#pragma unroll
  for (int i = 0; i < 32; i += 8) tile[ty + i][tx] = src[(long)(r0 + ty + i) * C + c0 + tx];
  __syncthreads();
#pragma unroll
  for (int i = 0; i < 32; i += 8)
    dst[(long)(c0 + ty + i) * R + r0 + tx] = __float2bfloat16(tile[tx][ty + i]);
}

// ---------------- persistent fused BiGRU ----------------
// 256 blocks x 256 threads, 1 block/CU. Weights resident: 128 KiB LDS + <=64 frags in VGPRs.
// blocks   0.. 63: unit0 fw L0 (blocks 0..31 also FC fw)
// blocks  64..127: unit1 bw L0 (blocks 64..95 also FC bw)
// blocks 128..191: unit2 fw L1
// blocks 192..255: unit3 bw L1
// LDS frag layout (uint4 frag idx *64 + lane):
//   [Wh-r 0..31][Wh-z 32..63][Wh-n 64..95] then
//   L1: [Wx-r 96..127]                      ; wreg[0..31]=Wx-z, wreg[32..63]=Wx-n
//   L0: [Wx-r 96..111][Wx-z 112..127]       ; wreg[0..15]=Wx-n, (FC) wreg[16..47]=FC-B
__global__ __launch_bounds__(256, 1)
void bigru_persist(char* __restrict__ ws, const float* __restrict__ xf,
                   const float* __restrict__ fwbx0, const float* __restrict__ fwbh0,
                   const float* __restrict__ fwbx1, const float* __restrict__ fwbh1,
                   const float* __restrict__ bwbx0, const float* __restrict__ bwbh0,
                   const float* __restrict__ bwbx1, const float* __restrict__ bwbh1,
                   const float* __restrict__ fcb, float* __restrict__ dout) {
  extern __shared__ uint4 wlds[];  // 131072 B = 8192 uint4

  const __hip_bfloat16* wt = (const __hip_bfloat16*)(ws + OFF_WT);
  __hip_bfloat16* h16 = (__hip_bfloat16*)(ws + OFF_H16);
  __hip_bfloat16* y0r = (__hip_bfloat16*)(ws + OFF_Y0R);
  __hip_bfloat16* y1r = (__hip_bfloat16*)(ws + OFF_Y1R);
  unsigned* barCnt = (unsigned*)(ws + OFF_BAR);          // 8 counters, stride 32 uints (128 B)
  unsigned* barTop = (unsigned*)(ws + OFF_BAR + 1024);
  unsigned* barGen = (unsigned*)(ws + OFF_BAR + 1152);

  const int tid = threadIdx.x;
  const int lane = tid & 63, wid = tid >> 6;
  const int rr = lane & 15, qq = lane >> 4;
  const int blk = blockIdx.x;
  const int unit = blk >> 6;
  const int j0 = (blk & 63) << 4;
  const bool isL1 = unit >= 2;
  const bool hasFC = (!isL1) && ((blk & 63) < 32);
  const int fcDir = unit;            // valid when hasFC: unit0->fw, unit1->bw
  const int j0f = (blk & 31) << 4;

  long eWh, eWx; int ldx; const float *bx, *bh; long dhOff;
  switch (unit) {
    case 0:  eWh = E_FW_WHT0; eWx = E_FW_WXT0; ldx = 512;  bx = fwbx0; bh = fwbh0; dhOff = OUT_FWH;         break;
    case 1:  eWh = E_BW_WHT0; eWx = E_BW_WXT0; ldx = 512;  bx = bwbx0; bh = bwbh0; dhOff = OUT_BWH;         break;
    case 2:  eWh = E_FW_WHT1; eWx = E_FW_WXT1; ldx = 1024; bx = fwbx1; bh = fwbh1; dhOff = OUT_FWH + 65536; break;
    default: eWh = E_BW_WHT1; eWx = E_BW_WXT1; ldx = 1024; bx = bwbx1; bh = bwbh1; dhOff = OUT_BWH + 65536; break;
  }

  // ---- one-time LDS weight staging (fragment order, conflict-free reads later) ----
  for (int f = wid; f < 128; f += 4) {
    const __hip_bfloat16* src;
    if (f < 96) {
      int g = f >> 5, kt = f & 31;                       // Wh gates r,z,n ; K=1024
      src = wt + eWh + (long)(g * 1024 + j0 + rr) * 1024 + kt * 32 + qq * 8;
    } else if (isL1) {
      int kt = f - 96;                                   // Wx-r ; K=1024
      src = wt + eWx + (long)(j0 + rr) * (long)ldx + kt * 32 + qq * 8;
    } else {
      int fx = f - 96, g = fx >> 4, kt = fx & 15;        // Wx-r (g=0), Wx-z (g=1) ; K=512
      src = wt + eWx + (long)(g * 1024 + j0 + rr) * (long)ldx + kt * 32 + qq * 8;
    }
    wlds[f * 64 + lane] = *(const uint4*)src;
  }

  // ---- one-time register-resident weights ----
  uint4 wreg[64];
  if (isL1) {
#pragma unroll
    for (int kt = 0; kt < 32; ++kt)  // Wx-z
      wreg[kt] = *(const uint4*)(wt + eWx + (long)(1024 + j0 + rr) * 1024 + kt * 32 + qq * 8);
#pragma unroll
    for (int kt = 0; kt < 32; ++kt)  // Wx-n
      wreg[32 + kt] = *(const uint4*)(wt + eWx + (long)(2048 + j0 + rr) * 1024 + kt * 32 + qq * 8);
  } else {
#pragma unroll
    for (int kt = 0; kt < 16; ++kt)  // Wx-n (L0)
      wreg[kt] = *(const uint4*)(wt + eWx + (long)(2048 + j0 + rr) * 512 + kt * 32 + qq * 8);
    if (hasFC) {
#pragma unroll
      for (int kt = 0; kt < 32; ++kt)
        wreg[16 + kt] = *(const uint4*)(wt + E_FCWT + (long)(j0f + rr) * 2048 + fcDir * 1024 + kt * 32 + qq * 8);
    }
  }

  // ---- hoisted per-lane constants ----
  const int j = j0 + rr;
  const float bxr = bx[j], bxz = bx[1024 + j], bxn = bx[2048 + j];
  const float bhr = bh[j], bhz = bh[1024 + j], bhn = bh[2048 + j];
  const float bvFC = hasFC ? fcb[j0f + rr] : 0.f;

  float hreg[4] = {0.f, 0.f, 0.f, 0.f};   // fp32 master h for rows wid*16+qq*4+g, col j
  const int lastS = isL1 ? 512 : 511;

  __syncthreads();

  for (int s = 0; s <= 513; ++s) {
    // ---------------- GRU ----------------
    bool act; int rp, t;
    if (!isL1) { act = (s <= 511);           rp = s & 1;       t = (unit == 0) ? s : 511 - s; }
    else       { act = (s >= 1 && s <= 512); rp = (s - 1) & 1; t = (unit == 2) ? s - 1 : 512 - s; }
    if (act) {
      const int wp = rp ^ 1;
      const char* pAh = (const char*)(h16 + (long)rp * 262144 + unit * 65536 + (wid * 16 + rr) * 1024 + qq * 8);

      f32x4 aR = {0.f,0.f,0.f,0.f}, aZ = {0.f,0.f,0.f,0.f};
      f32x4 aNH = {0.f,0.f,0.f,0.f}, aNX = {0.f,0.f,0.f,0.f};

      // ---- h-part: kt 0..31, batched depth-2 prefetch ----
      uint4 A0[8], A1[8];
#pragma unroll
      for (int i = 0; i < 8; ++i) A0[i] = *(const uint4*)(pAh + i * 64);
#pragma unroll
      for (int i = 0; i < 8; ++i) A1[i] = *(const uint4*)(pAh + (8 + i) * 64);
#pragma unroll
      for (int b = 0; b < 4; ++b) {
#pragma unroll
        for (int i = 0; i < 8; ++i) {
          const int kt = b * 8 + i;
          bf16x8 a = bc8((b & 1) ? A1[i] : A0[i]);
          aR  = MFMA16(a, bc8(wlds[kt * 64 + lane]), aR);
          aZ  = MFMA16(a, bc8(wlds[(32 + kt) * 64 + lane]), aZ);
          aNH = MFMA16(a, bc8(wlds[(64 + kt) * 64 + lane]), aNH);
        }
        if (b < 2) {
          uint4* dst = (b & 1) ? A1 : A0;
#pragma unroll
          for (int i = 0; i < 8; ++i) dst[i] = *(const uint4*)(pAh + ((b + 2) * 8 + i) * 64);
        }
      }

      // ---- x-part ----
      if (!isL1) {  // A = x fp32, K2=512 (16 kt), batches of 4 kt
        const char* pAx = (const char*)(xf + (long)(wid * 16 + rr) * 262144 + (long)t * 512 + qq * 8);
        uint4 X0[8], X1[8];
#pragma unroll
        for (int i = 0; i < 4; ++i) { X0[2*i] = *(const uint4*)(pAx + i * 128); X0[2*i+1] = *(const uint4*)(pAx + i * 128 + 16); }
#pragma unroll
        for (int i = 0; i < 4; ++i) { X1[2*i] = *(const uint4*)(pAx + (4+i) * 128); X1[2*i+1] = *(const uint4*)(pAx + (4+i) * 128 + 16); }
#pragma unroll
        for (int b = 0; b < 4; ++b) {
#pragma unroll
          for (int i = 0; i < 4; ++i) {
            const int kt = b * 4 + i;
            const uint4 r0 = (b & 1) ? X1[2*i] : X0[2*i];
            const uint4 r1 = (b & 1) ? X1[2*i+1] : X0[2*i+1];
            bf16x8 a = bc8(cvt8v(r0, r1));
            aR  = MFMA16(a, bc8(wlds[(96 + kt) * 64 + lane]), aR);
            aZ  = MFMA16(a, bc8(wlds[(112 + kt) * 64 + lane]), aZ);
            aNX = MFMA16(a, bc8(wreg[kt]), aNX);
          }
          if (b < 2) {
            uint4* dst = (b & 1) ? X1 : X0;
#pragma unroll
            for (int i = 0; i < 4; ++i) {
              dst[2*i]   = *(const uint4*)(pAx + ((b + 2) * 4 + i) * 128);
              dst[2*i+1] = *(const uint4*)(pAx + ((b + 2) * 4 + i) * 128 + 16);
            }
          }
        }
      } else {      // A = y0 ring bf16, K2=1024 (32 kt)
        const char* pAx = (const char*)(y0r + ((t & 1) * 2 + (unit & 1)) * 65536 + (wid * 16 + rr) * 1024 + qq * 8);
        uint4 X0[8], X1[8];
#pragma unroll
        for (int i = 0; i < 8; ++i) X0[i] = *(const uint4*)(pAx + i * 64);
#pragma unroll
        for (int i = 0; i < 8; ++i) X1[i] = *(const uint4*)(pAx + (8 + i) * 64);
#pragma unroll
        for (int b = 0; b < 4; ++b) {
#pragma unroll
          for (int i = 0; i < 8; ++i) {
            const int kt = b * 8 + i;
            bf16x8 a = bc8((b & 1) ? X1[i] : X0[i]);
            aR  = MFMA16(a, bc8(wlds[(96 + kt) * 64 + lane]), aR);
            aZ  = MFMA16(a, bc8(wreg[kt]), aZ);
            aNX = MFMA16(a, bc8(wreg[32 + kt]), aNX);
          }
          if (b < 2) {
            uint4* dst = (b & 1) ? X1 : X0;
#pragma unroll
            for (int i = 0; i < 8; ++i) dst[i] = *(const uint4*)(pAx + ((b + 2) * 8 + i) * 64);
          }
        }
      }

      // ---- epilogue: gates + state update ----
      __hip_bfloat16* hw = h16 + (long)wp * 262144 + unit * 65536;
      __hip_bfloat16* ring = (isL1 ? y1r : y0r) + ((t & 1) * 2 + (unit & 1)) * 65536;
#pragma unroll
      for (int g = 0; g < 4; ++g) {
        const int b = wid * 16 + qq * 4 + g;
        const float r_ = sig_(aR[g] + bxr + bhr);
        const float z_ = sig_(aZ[g] + bxz + bhz);
        const float n_ = tanh_(aNX[g] + bxn + r_ * (aNH[g] + bhn));
        const float hn2 = (1.f - z_) * n_ + z_ * hreg[g];
        hreg[g] = hn2;
        const __hip_bfloat16 hb = __float2bfloat16(hn2);
        hw[b * 1024 + j] = hb;
        ring[b * 1024 + j] = hb;
        if (s == lastS) dout[dhOff + b * 1024 + j] = hn2;
      }
    }

    // ---------------- FC (skew s-2 / 513-s) ----------------
    if (hasFC && s >= 2) {
      const int tf = fcDir ? (513 - s) : (s - 2);
      const char* pAf = (const char*)(y1r + ((tf & 1) * 2 + fcDir) * 65536 + (wid * 16 + rr) * 1024 + qq * 8);
      f32x4 fa = {0.f,0.f,0.f,0.f};
      uint4 F0[8], F1[8];
#pragma unroll
      for (int i = 0; i < 8; ++i) F0[i] = *(const uint4*)(pAf + i * 64);
#pragma unroll
      for (int i = 0; i < 8; ++i) F1[i] = *(const uint4*)(pAf + (8 + i) * 64);
#pragma unroll
      for (int b = 0; b < 4; ++b) {
#pragma unroll
        for (int i = 0; i < 8; ++i) {
          const int kt = b * 8 + i;
          bf16x8 a = bc8((b & 1) ? F1[i] : F0[i]);
          fa = MFMA16(a, bc8(wreg[16 + kt]), fa);
        }
        if (b < 2) {
          uint4* dst = (b & 1) ? F1 : F0;
#pragma unroll
          for (int i = 0; i < 8; ++i) dst[i] = *(const uint4*)(pAf + ((b + 2) * 8 + i) * 64);
        }
      }
      const int jf = j0f + rr;
      const bool first = fcDir ? (tf >= 256) : (tf <= 255);
#pragma unroll
      for (int g = 0; g < 4; ++g) {
        const int b = wid * 16 + qq * 4 + g;
        float* po = dout + (long)b * 262144 + (long)tf * 512 + jf;
        if (first) *po = fa[g] + bvFC;
        else       *po += fa[g];
      }
    }

    // ---------------- device-scope tree barrier ----------------
    if (s < 513) {
      __syncthreads();   // all threads' stores drained (vmcnt0 at barrier)
      if (tid == 0) {
        __builtin_amdgcn_fence(__ATOMIC_RELEASE, "agent");   // writeback: make writes L3-visible
        const int grp = blk >> 5;                            // 8 groups x 32 blocks
        bool pub = false;
        unsigned o1 = __hip_atomic_fetch_add(barCnt + grp * 32, 1u, __ATOMIC_ACQ_REL, __HIP_MEMORY_SCOPE_AGENT);
        if (o1 == (unsigned)(32 * (s + 1) - 1)) {
          unsigned o2 = __hip_atomic_fetch_add(barTop, 1u, __ATOMIC_ACQ_REL, __HIP_MEMORY_SCOPE_AGENT);
          if (o2 == (unsigned)(8 * (s + 1) - 1)) {
            __hip_atomic_store(barGen, (unsigned)(s + 1), __ATOMIC_RELEASE, __HIP_MEMORY_SCOPE_AGENT);
            pub = true;
          }
        }
        if (!pub) {
          while (__hip_atomic_load(barGen, __ATOMIC_RELAXED, __HIP_MEMORY_SCOPE_AGENT) < (unsigned)(s + 1)) {
            __builtin_amdgcn_s_sleep(1);
          }
        }
        __builtin_amdgcn_fence(__ATOMIC_ACQUIRE, "agent");   // invalidate stale L2 before next step's reads
      }
      __syncthreads();
    }
  }
}

extern "C" void kernel_launch(void* const* d_in, const int* in_sizes, int n_in,
                              void* d_out, int out_size, void* d_ws, size_t ws_size,
                              hipStream_t stream) {
  (void)in_sizes; (void)n_in; (void)out_size; (void)ws_size;
  char* ws = (char*)d_ws;
  const float* x = (const float*)d_in[0];
  __hip_bfloat16* wt = (__hip_bfloat16*)(ws + OFF_WT);

  // zero h state + barrier state (graph replays re-run these)
  hipMemsetAsync(ws + OFF_H16, 0, 1048576, stream);
  hipMemsetAsync(ws + OFF_BAR, 0, 2048, stream);

  // transpose-cast weights: src [K][3072] -> dst [3072][K] (and fc [2048][512] -> [512][2048])
  dim3 tb(32, 8);
  transpose_cast<<<dim3(96, 16), tb, 0, stream>>>((const float*)d_in[1],  wt + E_FW_WXT0, 512,  3072);
  transpose_cast<<<dim3(96, 32), tb, 0, stream>>>((const float*)d_in[2],  wt + E_FW_WHT0, 1024, 3072);
  transpose_cast<<<dim3(96, 32), tb, 0, stream>>>((const float*)d_in[5],  wt + E_FW_WXT1, 1024, 3072);
  transpose_cast<<<dim3(96, 32), tb, 0, stream>>>((const float*)d_in[6],  wt + E_FW_WHT1, 1024, 3072);
  transpose_cast<<<dim3(96, 16), tb, 0, stream>>>((const float*)d_in[9],  wt + E_BW_WXT0, 512,  3072);
  transpose_cast<<<dim3(96, 32), tb, 0, stream>>>((const float*)d_in[10], wt + E_BW_WHT0, 1024, 3072);
  transpose_cast<<<dim3(96, 32), tb, 0, stream>>>((const float*)d_in[13], wt + E_BW_WXT1, 1024, 3072);
  transpose_cast<<<dim3(96, 32), tb, 0, stream>>>((const float*)d_in[14], wt + E_BW_WHT1, 1024, 3072);
  transpose_cast<<<dim3(16, 64), tb, 0, stream>>>((const float*)d_in[17], wt + E_FCWT,    2048, 512);

  const float* fwbx0 = (const float*)d_in[3];
  const float* fwbh0 = (const float*)d_in[4];
  const float* fwbx1 = (const float*)d_in[7];
  const float* fwbh1 = (const float*)d_in[8];
  const float* bwbx0 = (const float*)d_in[11];
  const float* bwbh0 = (const float*)d_in[12];
  const float* bwbx1 = (const float*)d_in[15];
  const float* bwbh1 = (const float*)d_in[16];
  const float* fcb   = (const float*)d_in[18];
  float* dop = (float*)d_out;

  static bool attrSet = false;
  if (!attrSet) {
    hipFuncSetAttribute(reinterpret_cast<const void*>(bigru_persist),
                        hipFuncAttributeMaxDynamicSharedMemorySize, 131072);
    attrSet = true;
  }

  void* args[] = {&ws, &x, &fwbx0, &fwbh0, &fwbx1, &fwbh1,
                  &bwbx0, &bwbh0, &bwbx1, &bwbh1, &fcb, &dop};
  hipError_t e = hipLaunchCooperativeKernel(reinterpret_cast<const void*>(bigru_persist),
                                            dim3(256), dim3(256), args, 131072, stream);
  if (e != hipSuccess) {
    // fallback: plain launch (256 blocks on 256 CUs, 1 block/CU -> co-resident in practice)
    bigru_persist<<<dim3(256), dim3(256), 131072, stream>>>(
        ws, (const float*)x, fwbx0, fwbh0, fwbx1, fwbh1,
        bwbx0, bwbh0, bwbx1, bwbh1, fcb, dop);
  }
}

// Round 2
// 13155.182 us; speedup vs baseline: 1.3636x; 1.3636x over previous
//
#include <hip/hip_runtime.h>
#include <hip/hip_bf16.h>

typedef __attribute__((ext_vector_type(8))) short bf16x8;
typedef __attribute__((ext_vector_type(4))) float f32x4;

#define MFMA16(a,b,c) __builtin_amdgcn_mfma_f32_16x16x32_bf16((a),(b),(c),0,0,0)

// ---------------- workspace layout (byte offsets) ----------------
static constexpr long OFF_WT  = 0;           // bf16 transposed weights, 46,137,344 B
static constexpr long OFF_H16 = 46137344;    // h bf16 [2 parity][4 unit][64*1024] = 1,048,576 B
static constexpr long OFF_Y0R = 47185920;    // y0 ring bf16 [2 slot][2 dir][65536] = 524,288 B
static constexpr long OFF_Y1R = 47710208;    // y1 ring bf16 = 524,288 B
static constexpr long OFF_BAR = 48234496;    // flags[256] @ stride 64B (16 KiB), then barGen
// end < 48 MiB

// element offsets (bf16) within weight region
static constexpr long E_FW_WXT0 = 0;         // [3072][512]
static constexpr long E_FW_WHT0 = 1572864;   // [3072][1024]
static constexpr long E_FW_WXT1 = 4718592;
static constexpr long E_FW_WHT1 = 7864320;
static constexpr long E_BW_WXT0 = 11010048;
static constexpr long E_BW_WHT0 = 12582912;
static constexpr long E_BW_WXT1 = 15728640;
static constexpr long E_BW_WHT1 = 18874368;
static constexpr long E_FCWT    = 22020096;  // [512][2048]

static constexpr long OUT_FWH = 16777216;    // fw_h [2][64][1024] in d_out (float offsets)
static constexpr long OUT_BWH = 16908288;

__device__ __forceinline__ float sig_(float x) {
  x = fminf(fmaxf(x, -30.f), 30.f);
  return 1.f / (1.f + __expf(-x));
}
__device__ __forceinline__ float tanh_(float x) {
  x = fminf(fmaxf(x, -15.f), 15.f);
  float e = __expf(2.f * x);
  return (e - 1.f) / (e + 1.f);
}
__device__ __forceinline__ bf16x8 bc8(uint4 v) { return __builtin_bit_cast(bf16x8, v); }
__device__ __forceinline__ unsigned f2bfu(float f) {
  __hip_bfloat16 h = __float2bfloat16(f);
  return (unsigned)*(unsigned short*)&h;
}
// 8 fp32 (two uint4-of-float4) -> 8 packed bf16 (one uint4)
__device__ __forceinline__ uint4 cvt8v(uint4 u0, uint4 u1) {
  float4 a = __builtin_bit_cast(float4, u0);
  float4 b = __builtin_bit_cast(float4, u1);
  uint4 r;
  r.x = f2bfu(a.x) | (f2bfu(a.y) << 16);
  r.y = f2bfu(a.z) | (f2bfu(a.w) << 16);
  r.z = f2bfu(b.x) | (f2bfu(b.y) << 16);
  r.w = f2bfu(b.z) | (f2bfu(b.w) << 16);
  return r;
}

// ---- agent-coherent (L2-bypassing, sc1) accessors for cross-block mutable data ----
__device__ __forceinline__ uint4 cload16(const void* p) {
  const unsigned long long* q = (const unsigned long long*)p;
  unsigned long long lo = __hip_atomic_load(q,     __ATOMIC_RELAXED, __HIP_MEMORY_SCOPE_AGENT);
  unsigned long long hi = __hip_atomic_load(q + 1, __ATOMIC_RELAXED, __HIP_MEMORY_SCOPE_AGENT);
  uint4 r;
  r.x = (unsigned)lo; r.y = (unsigned)(lo >> 32);
  r.z = (unsigned)hi; r.w = (unsigned)(hi >> 32);
  return r;
}
__device__ __forceinline__ void cstore_bf(void* p, __hip_bfloat16 v) {
  __hip_atomic_store((unsigned short*)p, *(unsigned short*)&v,
                     __ATOMIC_RELAXED, __HIP_MEMORY_SCOPE_AGENT);
}

// ---------------- transpose+cast: src f32 [R][C] -> dst bf16 [C][R] ----------------
__global__ void transpose_cast(const float* __restrict__ src, __hip_bfloat16* __restrict__ dst,
                               int R, int C) {
  __shared__ float tile[32][33];
  int tx = threadIdx.x, ty = threadIdx.y;
  int c0 = blockIdx.x * 32, r0 = blockIdx.y * 32;
#pragma unroll
  for (int i = 0; i < 32; i += 8) tile[ty + i][tx] = src[(long)(r0 + ty + i) * C + c0 + tx];
  __syncthreads();
#pragma unroll
  for (int i = 0; i < 32; i += 8)
    dst[(long)(c0 + ty + i) * R + r0 + tx] = __float2bfloat16(tile[tx][ty + i]);
}

// ---------------- persistent fused BiGRU ----------------
// 256 blocks x 256 threads, 1 block/CU. Weights resident: 128 KiB LDS + <=64 frags in VGPRs.
// All cross-block mutable traffic (h16, rings, FC dout RMW, barrier flags) via sc1 atomics
// -> no cache-flush fences anywhere; x + weights stay L2-cached.
__global__ __launch_bounds__(256, 1)
void bigru_persist(char* __restrict__ ws, const float* __restrict__ xf,
                   const float* __restrict__ fwbx0, const float* __restrict__ fwbh0,
                   const float* __restrict__ fwbx1, const float* __restrict__ fwbh1,
                   const float* __restrict__ bwbx0, const float* __restrict__ bwbh0,
                   const float* __restrict__ bwbx1, const float* __restrict__ bwbh1,
                   const float* __restrict__ fcb, float* __restrict__ dout) {
  extern __shared__ uint4 wlds[];  // 131072 B = 8192 uint4

  const __hip_bfloat16* wt = (const __hip_bfloat16*)(ws + OFF_WT);
  __hip_bfloat16* h16 = (__hip_bfloat16*)(ws + OFF_H16);
  __hip_bfloat16* y0r = (__hip_bfloat16*)(ws + OFF_Y0R);
  __hip_bfloat16* y1r = (__hip_bfloat16*)(ws + OFF_Y1R);
  unsigned* flags  = (unsigned*)(ws + OFF_BAR);           // flags[blk] at blk*16 uints (64 B stride)
  unsigned* barGen = (unsigned*)(ws + OFF_BAR + 16384);

  const int tid = threadIdx.x;
  const int lane = tid & 63, wid = tid >> 6;
  const int rr = lane & 15, qq = lane >> 4;
  const int blk = blockIdx.x;
  const int unit = blk >> 6;
  const int j0 = (blk & 63) << 4;
  const bool isL1 = unit >= 2;
  const bool hasFC = (!isL1) && ((blk & 63) < 32);
  const int fcDir = unit;            // valid when hasFC: unit0->fw, unit1->bw
  const int j0f = (blk & 31) << 4;

  long eWh, eWx; int ldx; const float *bx, *bh; long dhOff;
  switch (unit) {
    case 0:  eWh = E_FW_WHT0; eWx = E_FW_WXT0; ldx = 512;  bx = fwbx0; bh = fwbh0; dhOff = OUT_FWH;         break;
    case 1:  eWh = E_BW_WHT0; eWx = E_BW_WXT0; ldx = 512;  bx = bwbx0; bh = bwbh0; dhOff = OUT_BWH;         break;
    case 2:  eWh = E_FW_WHT1; eWx = E_FW_WXT1; ldx = 1024; bx = fwbx1; bh = fwbh1; dhOff = OUT_FWH + 65536; break;
    default: eWh = E_BW_WHT1; eWx = E_BW_WXT1; ldx = 1024; bx = bwbx1; bh = bwbh1; dhOff = OUT_BWH + 65536; break;
  }

  // ---- one-time LDS weight staging ----
  for (int f = wid; f < 128; f += 4) {
    const __hip_bfloat16* src;
    if (f < 96) {
      int g = f >> 5, kt = f & 31;                       // Wh gates r,z,n ; K=1024
      src = wt + eWh + (long)(g * 1024 + j0 + rr) * 1024 + kt * 32 + qq * 8;
    } else if (isL1) {
      int kt = f - 96;                                   // Wx-r ; K=1024
      src = wt + eWx + (long)(j0 + rr) * (long)ldx + kt * 32 + qq * 8;
    } else {
      int fx = f - 96, g = fx >> 4, kt = fx & 15;        // Wx-r (g=0), Wx-z (g=1) ; K=512
      src = wt + eWx + (long)(g * 1024 + j0 + rr) * (long)ldx + kt * 32 + qq * 8;
    }
    wlds[f * 64 + lane] = *(const uint4*)src;
  }

  // ---- one-time register-resident weights ----
  uint4 wreg[64];
  if (isL1) {
#pragma unroll
    for (int kt = 0; kt < 32; ++kt)  // Wx-z
      wreg[kt] = *(const uint4*)(wt + eWx + (long)(1024 + j0 + rr) * 1024 + kt * 32 + qq * 8);
#pragma unroll
    for (int kt = 0; kt < 32; ++kt)  // Wx-n
      wreg[32 + kt] = *(const uint4*)(wt + eWx + (long)(2048 + j0 + rr) * 1024 + kt * 32 + qq * 8);
  } else {
#pragma unroll
    for (int kt = 0; kt < 16; ++kt)  // Wx-n (L0)
      wreg[kt] = *(const uint4*)(wt + eWx + (long)(2048 + j0 + rr) * 512 + kt * 32 + qq * 8);
    if (hasFC) {
#pragma unroll
      for (int kt = 0; kt < 32; ++kt)
        wreg[16 + kt] = *(const uint4*)(wt + E_FCWT + (long)(j0f + rr) * 2048 + fcDir * 1024 + kt * 32 + qq * 8);
    }
  }

  // ---- hoisted per-lane constants ----
  const int j = j0 + rr;
  const float bxr = bx[j], bxz = bx[1024 + j], bxn = bx[2048 + j];
  const float bhr = bh[j], bhz = bh[1024 + j], bhn = bh[2048 + j];
  const float bvFC = hasFC ? fcb[j0f + rr] : 0.f;

  float hreg[4] = {0.f, 0.f, 0.f, 0.f};   // fp32 master h for rows wid*16+qq*4+g, col j
  const int lastS = isL1 ? 512 : 511;

  __syncthreads();

  for (int s = 0; s <= 513; ++s) {
    // ---------------- GRU ----------------
    bool act; int rp, t;
    if (!isL1) { act = (s <= 511);           rp = s & 1;       t = (unit == 0) ? s : 511 - s; }
    else       { act = (s >= 1 && s <= 512); rp = (s - 1) & 1; t = (unit == 2) ? s - 1 : 512 - s; }
    if (act) {
      const int wp = rp ^ 1;
      const char* pAh = (const char*)(h16 + (long)rp * 262144 + unit * 65536 + (wid * 16 + rr) * 1024 + qq * 8);

      f32x4 aR = {0.f,0.f,0.f,0.f}, aZ = {0.f,0.f,0.f,0.f};
      f32x4 aNH = {0.f,0.f,0.f,0.f}, aNX = {0.f,0.f,0.f,0.f};

      // ---- h-part: kt 0..31, batched depth-2 prefetch (coherent loads) ----
      uint4 A0[8], A1[8];
#pragma unroll
      for (int i = 0; i < 8; ++i) A0[i] = cload16(pAh + i * 64);
#pragma unroll
      for (int i = 0; i < 8; ++i) A1[i] = cload16(pAh + (8 + i) * 64);
#pragma unroll
      for (int b = 0; b < 4; ++b) {
#pragma unroll
        for (int i = 0; i < 8; ++i) {
          const int kt = b * 8 + i;
          bf16x8 a = bc8((b & 1) ? A1[i] : A0[i]);
          aR  = MFMA16(a, bc8(wlds[kt * 64 + lane]), aR);
          aZ  = MFMA16(a, bc8(wlds[(32 + kt) * 64 + lane]), aZ);
          aNH = MFMA16(a, bc8(wlds[(64 + kt) * 64 + lane]), aNH);
        }
        if (b < 2) {
          uint4* dst = (b & 1) ? A1 : A0;
#pragma unroll
          for (int i = 0; i < 8; ++i) dst[i] = cload16(pAh + ((b + 2) * 8 + i) * 64);
        }
      }

      // ---- x-part ----
      if (!isL1) {  // A = x fp32 (read-only input: normal cached loads), K2=512
        const char* pAx = (const char*)(xf + (long)(wid * 16 + rr) * 262144 + (long)t * 512 + qq * 8);
        uint4 X0[8], X1[8];
#pragma unroll
        for (int i = 0; i < 4; ++i) { X0[2*i] = *(const uint4*)(pAx + i * 128); X0[2*i+1] = *(const uint4*)(pAx + i * 128 + 16); }
#pragma unroll
        for (int i = 0; i < 4; ++i) { X1[2*i] = *(const uint4*)(pAx + (4+i) * 128); X1[2*i+1] = *(const uint4*)(pAx + (4+i) * 128 + 16); }
#pragma unroll
        for (int b = 0; b < 4; ++b) {
#pragma unroll
          for (int i = 0; i < 4; ++i) {
            const int kt = b * 4 + i;
            const uint4 r0 = (b & 1) ? X1[2*i] : X0[2*i];
            const uint4 r1 = (b & 1) ? X1[2*i+1] : X0[2*i+1];
            bf16x8 a = bc8(cvt8v(r0, r1));
            aR  = MFMA16(a, bc8(wlds[(96 + kt) * 64 + lane]), aR);
            aZ  = MFMA16(a, bc8(wlds[(112 + kt) * 64 + lane]), aZ);
            aNX = MFMA16(a, bc8(wreg[kt]), aNX);
          }
          if (b < 2) {
            uint4* dst = (b & 1) ? X1 : X0;
#pragma unroll
            for (int i = 0; i < 4; ++i) {
              dst[2*i]   = *(const uint4*)(pAx + ((b + 2) * 4 + i) * 128);
              dst[2*i+1] = *(const uint4*)(pAx + ((b + 2) * 4 + i) * 128 + 16);
            }
          }
        }
      } else {      // A = y0 ring bf16 (cross-block: coherent loads), K2=1024
        const char* pAx = (const char*)(y0r + ((t & 1) * 2 + (unit & 1)) * 65536 + (wid * 16 + rr) * 1024 + qq * 8);
        uint4 X0[8], X1[8];
#pragma unroll
        for (int i = 0; i < 8; ++i) X0[i] = cload16(pAx + i * 64);
#pragma unroll
        for (int i = 0; i < 8; ++i) X1[i] = cload16(pAx + (8 + i) * 64);
#pragma unroll
        for (int b = 0; b < 4; ++b) {
#pragma unroll
          for (int i = 0; i < 8; ++i) {
            const int kt = b * 8 + i;
            bf16x8 a = bc8((b & 1) ? X1[i] : X0[i]);
            aR  = MFMA16(a, bc8(wlds[(96 + kt) * 64 + lane]), aR);
            aZ  = MFMA16(a, bc8(wreg[kt]), aZ);
            aNX = MFMA16(a, bc8(wreg[32 + kt]), aNX);
          }
          if (b < 2) {
            uint4* dst = (b & 1) ? X1 : X0;
#pragma unroll
            for (int i = 0; i < 8; ++i) dst[i] = cload16(pAx + ((b + 2) * 8 + i) * 64);
          }
        }
      }

      // ---- epilogue: gates + state update (coherent stores) ----
      __hip_bfloat16* hw = h16 + (long)wp * 262144 + unit * 65536;
      __hip_bfloat16* ring = (isL1 ? y1r : y0r) + ((t & 1) * 2 + (unit & 1)) * 65536;
#pragma unroll
      for (int g = 0; g < 4; ++g) {
        const int b = wid * 16 + qq * 4 + g;
        const float r_ = sig_(aR[g] + bxr + bhr);
        const float z_ = sig_(aZ[g] + bxz + bhz);
        const float n_ = tanh_(aNX[g] + bxn + r_ * (aNH[g] + bhn));
        const float hn2 = (1.f - z_) * n_ + z_ * hreg[g];
        hreg[g] = hn2;
        const __hip_bfloat16 hb = __float2bfloat16(hn2);
        cstore_bf(hw + b * 1024 + j, hb);
        cstore_bf(ring + b * 1024 + j, hb);
        if (s == lastS) dout[dhOff + b * 1024 + j] = hn2;   // host-only: normal store
      }
    }

    // ---------------- FC (skew s-2 / 513-s) ----------------
    if (hasFC && s >= 2) {
      const int tf = fcDir ? (513 - s) : (s - 2);
      const char* pAf = (const char*)(y1r + ((tf & 1) * 2 + fcDir) * 65536 + (wid * 16 + rr) * 1024 + qq * 8);
      f32x4 fa = {0.f,0.f,0.f,0.f};
      uint4 F0[8], F1[8];
#pragma unroll
      for (int i = 0; i < 8; ++i) F0[i] = cload16(pAf + i * 64);
#pragma unroll
      for (int i = 0; i < 8; ++i) F1[i] = cload16(pAf + (8 + i) * 64);
#pragma unroll
      for (int b = 0; b < 4; ++b) {
#pragma unroll
        for (int i = 0; i < 8; ++i) {
          const int kt = b * 8 + i;
          bf16x8 a = bc8((b & 1) ? F1[i] : F0[i]);
          fa = MFMA16(a, bc8(wreg[16 + kt]), fa);
        }
        if (b < 2) {
          uint4* dst = (b & 1) ? F1 : F0;
#pragma unroll
          for (int i = 0; i < 8; ++i) dst[i] = cload16(pAf + ((b + 2) * 8 + i) * 64);
        }
      }
      const int jf = j0f + rr;
      const bool first = fcDir ? (tf >= 256) : (tf <= 255);
#pragma unroll
      for (int g = 0; g < 4; ++g) {
        const int b = wid * 16 + qq * 4 + g;
        float* po = dout + (long)b * 262144 + (long)tf * 512 + jf;
        if (first) {
          __hip_atomic_store(po, fa[g] + bvFC, __ATOMIC_RELAXED, __HIP_MEMORY_SCOPE_AGENT);
        } else {
          float prev = __hip_atomic_load(po, __ATOMIC_RELAXED, __HIP_MEMORY_SCOPE_AGENT);
          __hip_atomic_store(po, prev + fa[g], __ATOMIC_RELAXED, __HIP_MEMORY_SCOPE_AGENT);
        }
      }
    }

    // ---------------- device-scope parallel-flag barrier (no fences, no RMW) ----------------
    if (s < 513) {
      __syncthreads();   // compiler emits s_waitcnt vmcnt(0) before s_barrier: all sc1 stores are at L3
      const unsigned gen = (unsigned)(s + 1);
      if (blk == 0) {
        if (tid == 0)
          __hip_atomic_store(flags, gen, __ATOMIC_RELAXED, __HIP_MEMORY_SCOPE_AGENT);
        while (__hip_atomic_load(flags + tid * 16, __ATOMIC_RELAXED, __HIP_MEMORY_SCOPE_AGENT) < gen)
          __builtin_amdgcn_s_sleep(2);
        __syncthreads();
        if (tid == 0)
          __hip_atomic_store(barGen, gen, __ATOMIC_RELAXED, __HIP_MEMORY_SCOPE_AGENT);
      } else {
        if (tid == 0) {
          __hip_atomic_store(flags + blk * 16, gen, __ATOMIC_RELAXED, __HIP_MEMORY_SCOPE_AGENT);
          while (__hip_atomic_load(barGen, __ATOMIC_RELAXED, __HIP_MEMORY_SCOPE_AGENT) < gen)
            __builtin_amdgcn_s_sleep(2);
        }
        __syncthreads();
      }
    }
  }
}

extern "C" void kernel_launch(void* const* d_in, const int* in_sizes, int n_in,
                              void* d_out, int out_size, void* d_ws, size_t ws_size,
                              hipStream_t stream) {
  (void)in_sizes; (void)n_in; (void)out_size; (void)ws_size;
  char* ws = (char*)d_ws;
  const float* x = (const float*)d_in[0];
  __hip_bfloat16* wt = (__hip_bfloat16*)(ws + OFF_WT);

  // zero h state + barrier flags (graph replays re-run these)
  hipMemsetAsync(ws + OFF_H16, 0, 1048576, stream);
  hipMemsetAsync(ws + OFF_BAR, 0, 16448, stream);

  // transpose-cast weights: src [K][3072] -> dst [3072][K] (and fc [2048][512] -> [512][2048])
  dim3 tb(32, 8);
  transpose_cast<<<dim3(96, 16), tb, 0, stream>>>((const float*)d_in[1],  wt + E_FW_WXT0, 512,  3072);
  transpose_cast<<<dim3(96, 32), tb, 0, stream>>>((const float*)d_in[2],  wt + E_FW_WHT0, 1024, 3072);
  transpose_cast<<<dim3(96, 32), tb, 0, stream>>>((const float*)d_in[5],  wt + E_FW_WXT1, 1024, 3072);
  transpose_cast<<<dim3(96, 32), tb, 0, stream>>>((const float*)d_in[6],  wt + E_FW_WHT1, 1024, 3072);
  transpose_cast<<<dim3(96, 16), tb, 0, stream>>>((const float*)d_in[9],  wt + E_BW_WXT0, 512,  3072);
  transpose_cast<<<dim3(96, 32), tb, 0, stream>>>((const float*)d_in[10], wt + E_BW_WHT0, 1024, 3072);
  transpose_cast<<<dim3(96, 32), tb, 0, stream>>>((const float*)d_in[13], wt + E_BW_WXT1, 1024, 3072);
  transpose_cast<<<dim3(96, 32), tb, 0, stream>>>((const float*)d_in[14], wt + E_BW_WHT1, 1024, 3072);
  transpose_cast<<<dim3(16, 64), tb, 0, stream>>>((const float*)d_in[17], wt + E_FCWT,    2048, 512);

  const float* fwbx0 = (const float*)d_in[3];
  const float* fwbh0 = (const float*)d_in[4];
  const float* fwbx1 = (const float*)d_in[7];
  const float* fwbh1 = (const float*)d_in[8];
  const float* bwbx0 = (const float*)d_in[11];
  const float* bwbh0 = (const float*)d_in[12];
  const float* bwbx1 = (const float*)d_in[15];
  const float* bwbh1 = (const float*)d_in[16];
  const float* fcb   = (const float*)d_in[18];
  float* dop = (float*)d_out;

  static bool attrSet = false;
  if (!attrSet) {
    hipFuncSetAttribute(reinterpret_cast<const void*>(bigru_persist),
                        hipFuncAttributeMaxDynamicSharedMemorySize, 131072);
    attrSet = true;
  }

  void* args[] = {&ws, &x, &fwbx0, &fwbh0, &fwbx1, &fwbh1,
                  &bwbx0, &bwbh0, &bwbx1, &bwbh1, &fcb, &dop};
  hipError_t e = hipLaunchCooperativeKernel(reinterpret_cast<const void*>(bigru_persist),
                                            dim3(256), dim3(256), args, 131072, stream);
  if (e != hipSuccess) {
    bigru_persist<<<dim3(256), dim3(256), 131072, stream>>>(
        ws, (const float*)x, fwbx0, fwbh0, fwbx1, fwbh1,
        bwbx0, bwbh0, bwbx1, bwbh1, fcb, dop);
  }
}

// Round 4
// 8203.774 us; speedup vs baseline: 2.1865x; 1.6036x over previous
//
#include <hip/hip_runtime.h>
#include <hip/hip_bf16.h>

typedef __attribute__((ext_vector_type(8))) short bf16x8;
typedef __attribute__((ext_vector_type(4))) float f32x4;
typedef __attribute__((ext_vector_type(4))) unsigned int u32x4;

#define MFMA16(a,b,c) __builtin_amdgcn_mfma_f32_16x16x32_bf16((a),(b),(c),0,0,0)

// coherent (agent-scope, L2-bypass) asm memory ops — batched issue, counted waits.
// NOTE: asm "v" operands must be ext_vector types (u32x4), not struct uint4.
#define GLOAD(dst, ptr)  asm volatile("global_load_dwordx4 %0, %1, off sc1" : "=v"(dst) : "v"(ptr))
#define GLOADD(dst, ptr) asm volatile("global_load_dword %0, %1, off sc1"   : "=v"(dst) : "v"(ptr))
#define GSTORE4(ptr, v)  asm volatile("global_store_dwordx4 %0, %1, off sc1" :: "v"(ptr), "v"(v) : "memory")
#define GSTORED(ptr, v)  asm volatile("global_store_dword %0, %1, off sc1"   :: "v"(ptr), "v"(v) : "memory")
#define VMWAIT8 do { asm volatile("s_waitcnt vmcnt(8)" ::: "memory"); __builtin_amdgcn_sched_barrier(0); } while(0)
#define VMWAIT0 do { asm volatile("s_waitcnt vmcnt(0)" ::: "memory"); __builtin_amdgcn_sched_barrier(0); } while(0)

// ---------------- workspace layout (byte offsets) ----------------
static constexpr long OFF_WT  = 0;           // bf16 transposed weights, 46,137,344 B
static constexpr long OFF_H16 = 46137344;    // h bf16 [2 parity][4 unit][64][1024] = 1,048,576 B
static constexpr long OFF_BAR = 48234496;    // flags[256]@64B stride (16 KiB) + barGenA[8]@64B
// end < 48 MiB

// element offsets (bf16) within weight region
static constexpr long E_FW_WXT0 = 0;         // [3072][512]
static constexpr long E_FW_WHT0 = 1572864;   // [3072][1024]
static constexpr long E_FW_WXT1 = 4718592;
static constexpr long E_FW_WHT1 = 7864320;
static constexpr long E_BW_WXT0 = 11010048;
static constexpr long E_BW_WHT0 = 12582912;
static constexpr long E_BW_WXT1 = 15728640;
static constexpr long E_BW_WHT1 = 18874368;
static constexpr long E_FCWT    = 22020096;  // [512][2048]

static constexpr long OUT_FWH = 16777216;    // fw_h [2][64][1024] in d_out (float offsets)
static constexpr long OUT_BWH = 16908288;

__device__ __forceinline__ float sig_(float x) {
  x = fminf(fmaxf(x, -30.f), 30.f);
  return 1.f / (1.f + __expf(-x));
}
__device__ __forceinline__ float tanh_(float x) {
  x = fminf(fmaxf(x, -15.f), 15.f);
  float e = __expf(2.f * x);
  return (e - 1.f) / (e + 1.f);
}
__device__ __forceinline__ bf16x8 bc8(uint4 v) { return __builtin_bit_cast(bf16x8, v); }
__device__ __forceinline__ bf16x8 bc8(u32x4 v) { return __builtin_bit_cast(bf16x8, v); }
__device__ __forceinline__ unsigned f2bfu(float f) {
  __hip_bfloat16 h = __float2bfloat16(f);
  return (unsigned)*(unsigned short*)&h;
}
// 8 fp32 (two uint4-of-float4) -> 8 packed bf16 (one uint4)
__device__ __forceinline__ uint4 cvt8v(uint4 u0, uint4 u1) {
  float4 a = __builtin_bit_cast(float4, u0);
  float4 b = __builtin_bit_cast(float4, u1);
  uint4 r;
  r.x = f2bfu(a.x) | (f2bfu(a.y) << 16);
  r.y = f2bfu(a.z) | (f2bfu(a.w) << 16);
  r.z = f2bfu(b.x) | (f2bfu(b.y) << 16);
  r.w = f2bfu(b.z) | (f2bfu(b.w) << 16);
  return r;
}

// ---------------- transpose+cast: src f32 [R][C] -> dst bf16 [C][R] ----------------
__global__ void transpose_cast(const float* __restrict__ src, __hip_bfloat16* __restrict__ dst,
                               int R, int C) {
  __shared__ float tile[32][33];
  int tx = threadIdx.x, ty = threadIdx.y;
  int c0 = blockIdx.x * 32, r0 = blockIdx.y * 32;
#pragma unroll
  for (int i = 0; i < 32; i += 8) tile[ty + i][tx] = src[(long)(r0 + ty + i) * C + c0 + tx];
  __syncthreads();
#pragma unroll
  for (int i = 0; i < 32; i += 8)
    dst[(long)(c0 + ty + i) * R + r0 + tx] = __float2bfloat16(tile[tx][ty + i]);
}

// ---------------- persistent fused BiGRU ----------------
// 256 blocks x 512 threads (8 waves), 1 block/CU.
// waves 0-3: K-half 0 (batch quarters 0-3); waves 4-7: K-half 1; LDS reduce of partials.
// blocks   0.. 63: unit0 fw L0 (blocks  0..31 also FC fw)
// blocks  64..127: unit1 bw L0 (blocks 64..95 also FC bw)
// blocks 128..191: unit2 fw L1;  192..255: unit3 bw L1
// All cross-block state lives in h16 [parity][unit][64][1024] (sc1 asm ops, batched).
__global__ __launch_bounds__(512, 1)
void bigru_persist(char* __restrict__ ws, const float* __restrict__ xf,
                   const float* __restrict__ fwbx0, const float* __restrict__ fwbh0,
                   const float* __restrict__ fwbx1, const float* __restrict__ fwbh1,
                   const float* __restrict__ bwbx0, const float* __restrict__ bwbh0,
                   const float* __restrict__ bwbx1, const float* __restrict__ bwbh1,
                   const float* __restrict__ fcb, float* __restrict__ dout) {
  extern __shared__ uint4 wlds[];            // 131072 B = 128 weight frags * 64 lanes * 16B
  __shared__ float redu[4 * 64 * 17];        // cross-K-half reduce, +17 pad (17408 B)
  __shared__ unsigned short stg[64 * 16];    // h store staging (2048 B)

  char* h16b = ws + OFF_H16;
  const __hip_bfloat16* wt = (const __hip_bfloat16*)(ws + OFF_WT);
  unsigned* flags   = (unsigned*)(ws + OFF_BAR);            // [blk] stride 16 uints
  unsigned* barGenA = (unsigned*)(ws + OFF_BAR + 16384);    // 8 replicated gen lines

  const int tid  = threadIdx.x;
  const int lane = tid & 63;
  const int wid  = tid >> 6;      // 0..7
  const int wsub = wid & 3;       // batch quarter (rows wsub*16+rr)
  const int khalf = wid >> 2;     // K half
  const int rr = lane & 15, qq = lane >> 4;
  const int blk = blockIdx.x;
  const int unit = blk >> 6;
  const int j0 = (blk & 63) << 4;
  const bool isL1 = unit >= 2;
  const bool hasFC = (!isL1) && ((blk & 63) < 32);
  const int fcDir = unit;         // valid when hasFC
  const int j0f = (blk & 31) << 4;

  long eWh, eWx; int ldx; const float *bx, *bh; long dhOff;
  switch (unit) {
    case 0:  eWh = E_FW_WHT0; eWx = E_FW_WXT0; ldx = 512;  bx = fwbx0; bh = fwbh0; dhOff = OUT_FWH;         break;
    case 1:  eWh = E_BW_WHT0; eWx = E_BW_WXT0; ldx = 512;  bx = bwbx0; bh = bwbh0; dhOff = OUT_BWH;         break;
    case 2:  eWh = E_FW_WHT1; eWx = E_FW_WXT1; ldx = 1024; bx = fwbx1; bh = fwbh1; dhOff = OUT_FWH + 65536; break;
    default: eWh = E_BW_WHT1; eWx = E_BW_WXT1; ldx = 1024; bx = bwbx1; bh = bwbh1; dhOff = OUT_BWH + 65536; break;
  }

  // ---- one-time LDS weight staging (128 frags: Wh r/z/n = 0..95, Wx-r(+z for L0) = 96..127) ----
  for (int f = wid; f < 128; f += 8) {
    const __hip_bfloat16* src;
    if (f < 96) {
      int g = f >> 5, kt = f & 31;                       // Wh gates r,z,n ; K=1024
      src = wt + eWh + (long)(g * 1024 + j0 + rr) * 1024 + kt * 32 + qq * 8;
    } else if (isL1) {
      int kt = f - 96;                                   // Wx-r ; K=1024
      src = wt + eWx + (long)(j0 + rr) * (long)ldx + kt * 32 + qq * 8;
    } else {
      int fx = f - 96, g = fx >> 4, kt = fx & 15;        // Wx-r (g=0), Wx-z (g=1) ; K=512
      src = wt + eWx + (long)(g * 1024 + j0 + rr) * (long)ldx + kt * 32 + qq * 8;
    }
    wlds[f * 64 + lane] = *(const uint4*)src;
  }

  // ---- register weights (per-thread K-half slice only => no spills) ----
  // L1: wreg[0..15] = Wx-n half. L0: wreg[0..7] = Wx-n half; wreg[8..23] = FC half.
  uint4 wreg[24];
  if (isL1) {
#pragma unroll
    for (int k = 0; k < 16; ++k)
      wreg[k] = *(const uint4*)(wt + eWx + (long)(2048 + j0 + rr) * 1024 + (khalf * 16 + k) * 32 + qq * 8);
  } else {
#pragma unroll
    for (int k = 0; k < 8; ++k)
      wreg[k] = *(const uint4*)(wt + eWx + (long)(2048 + j0 + rr) * 512 + (khalf * 8 + k) * 32 + qq * 8);
    if (hasFC) {
#pragma unroll
      for (int k = 0; k < 16; ++k)
        wreg[8 + k] = *(const uint4*)(wt + E_FCWT + (long)(j0f + rr) * 2048 + fcDir * 1024 + (khalf * 16 + k) * 32 + qq * 8);
    }
  }
  // L1 Wx-z slice: per-step L2-cached loads (read-only weights stay in L2)
  const char* wzb = (const char*)(wt + eWx + (long)(1024 + j0 + rr) * 1024) + khalf * 1024 + qq * 16;

  // ---- hoisted per-lane constants ----
  const int j = j0 + rr;
  const float bxr = bx[j], bxz = bx[1024 + j], bxn = bx[2048 + j];
  const float bhr = bh[j], bhz = bh[1024 + j], bhn = bh[2048 + j];
  const float bvFC = hasFC ? fcb[j0f + rr] : 0.f;

  float hreg[4] = {0.f, 0.f, 0.f, 0.f};   // fp32 master h (kept by waves 0-3)
  const int lastS = isL1 ? 512 : 511;

  __syncthreads();

  for (int s = 0; s <= 513; ++s) {
    // ---------------- GRU ----------------
    bool act; int rp, t;
    if (!isL1) { act = (s <= 511);           rp = s & 1;       t = (unit == 0) ? s : 511 - s; }
    else       { act = (s >= 1 && s <= 512); rp = (s - 1) & 1; t = (unit == 2) ? s - 1 : 512 - s; }
    if (act) {
      const int wp = rp ^ 1;
      f32x4 aR = {0.f,0.f,0.f,0.f}, aZ = {0.f,0.f,0.f,0.f};
      f32x4 aNH = {0.f,0.f,0.f,0.f}, aNX = {0.f,0.f,0.f,0.f};

      { // ---- h-part: 16 frags per wave (this wave's K-half), batched sc1 loads ----
        const char* pAh = h16b + (long)rp * 524288 + unit * 131072 + (wsub * 16 + rr) * 2048 + khalf * 1024 + qq * 16;
        u32x4 A[16];
#pragma unroll
        for (int i = 0; i < 16; ++i) GLOAD(A[i], pAh + i * 64);
        VMWAIT8;
#pragma unroll
        for (int i = 0; i < 8; ++i) {
          const int kt = khalf * 16 + i;
          bf16x8 a = bc8(A[i]);
          aR  = MFMA16(a, bc8(wlds[kt * 64 + lane]), aR);
          aZ  = MFMA16(a, bc8(wlds[(32 + kt) * 64 + lane]), aZ);
          aNH = MFMA16(a, bc8(wlds[(64 + kt) * 64 + lane]), aNH);
        }
        VMWAIT0;
#pragma unroll
        for (int i = 8; i < 16; ++i) {
          const int kt = khalf * 16 + i;
          bf16x8 a = bc8(A[i]);
          aR  = MFMA16(a, bc8(wlds[kt * 64 + lane]), aR);
          aZ  = MFMA16(a, bc8(wlds[(32 + kt) * 64 + lane]), aZ);
          aNH = MFMA16(a, bc8(wlds[(64 + kt) * 64 + lane]), aNH);
        }
      }

      if (!isL1) {
        // ---- x-part: read-only fp32 x, normal cached loads + cvt (compiler-scheduled) ----
        const char* pAx = (const char*)xf + (long)(wsub * 16 + rr) * 1048576 + (long)t * 2048 + khalf * 1024 + qq * 32;
#pragma unroll
        for (int i = 0; i < 8; ++i) {
          uint4 u0 = *(const uint4*)(pAx + i * 128);
          uint4 u1 = *(const uint4*)(pAx + i * 128 + 16);
          const int ktg = khalf * 8 + i;
          bf16x8 a = bc8(cvt8v(u0, u1));
          aR  = MFMA16(a, bc8(wlds[(96 + ktg) * 64 + lane]), aR);
          aZ  = MFMA16(a, bc8(wlds[(112 + ktg) * 64 + lane]), aZ);
          aNX = MFMA16(a, bc8(wreg[i]), aNX);
        }
      } else {
        // ---- y-part: A = L0 output h16[s&1][unit-2], batched sc1 loads ----
        const char* pAy = h16b + (long)(s & 1) * 524288 + (unit - 2) * 131072 + (wsub * 16 + rr) * 2048 + khalf * 1024 + qq * 16;
        u32x4 A[16];
#pragma unroll
        for (int i = 0; i < 16; ++i) GLOAD(A[i], pAy + i * 64);
        VMWAIT0;
#pragma unroll
        for (int i = 0; i < 16; ++i) {
          const int ktg = khalf * 16 + i;
          bf16x8 a = bc8(A[i]);
          uint4 wz = *(const uint4*)(wzb + i * 64);   // L2-cached Wx-z
          aR  = MFMA16(a, bc8(wlds[(96 + ktg) * 64 + lane]), aR);
          aZ  = MFMA16(a, bc8(wz), aZ);
          aNX = MFMA16(a, bc8(wreg[i]), aNX);
        }
      }

      // ---- cross-K-half reduce + epilogue ----
      __syncthreads();
      if (khalf) {
        float* rb = &redu[(wsub * 64 + lane) * 17];
#pragma unroll
        for (int g = 0; g < 4; ++g) { rb[g] = aR[g]; rb[4 + g] = aZ[g]; rb[8 + g] = aNH[g]; rb[12 + g] = aNX[g]; }
      }
      __syncthreads();
      if (!khalf) {
        const float* rb = &redu[(wsub * 64 + lane) * 17];
#pragma unroll
        for (int g = 0; g < 4; ++g) {
          const int row = wsub * 16 + qq * 4 + g;
          const float r_ = sig_((aR[g] + rb[g]) + bxr + bhr);
          const float z_ = sig_((aZ[g] + rb[4 + g]) + bxz + bhz);
          const float n_ = tanh_((aNX[g] + rb[12 + g]) + bxn + r_ * ((aNH[g] + rb[8 + g]) + bhn));
          const float hn2 = (1.f - z_) * n_ + z_ * hreg[g];
          hreg[g] = hn2;
          const __hip_bfloat16 hb = __float2bfloat16(hn2);
          stg[row * 16 + rr] = *(const unsigned short*)&hb;
          if (s == lastS) dout[dhOff + (long)row * 1024 + j] = hn2;  // host-only
        }
      }
      __syncthreads();
      // ---- wide coherent h store: 128 x 16B per block ----
      if (tid < 128) {
        const int row = tid >> 1, seg = tid & 1;
        u32x4 v = *(const u32x4*)&stg[row * 16 + seg * 8];
        char* pd = h16b + (long)wp * 524288 + unit * 131072 + row * 2048 + j0 * 2 + seg * 16;
        GSTORE4(pd, v);
      }
    }

    // ---------------- FC (reads h16[(s-1)&1][unit 2|3]) ----------------
    if (hasFC && s >= 2) {
      const int tf = fcDir ? (513 - s) : (s - 2);
      const char* pAf = h16b + (long)((s - 1) & 1) * 524288 + (2 + fcDir) * 131072 + (wsub * 16 + rr) * 2048 + khalf * 1024 + qq * 16;
      f32x4 fa = {0.f,0.f,0.f,0.f};
      u32x4 F[16];
#pragma unroll
      for (int i = 0; i < 16; ++i) GLOAD(F[i], pAf + i * 64);
      VMWAIT8;
#pragma unroll
      for (int i = 0; i < 8; ++i) fa = MFMA16(bc8(F[i]), bc8(wreg[8 + i]), fa);
      VMWAIT0;
#pragma unroll
      for (int i = 8; i < 16; ++i) fa = MFMA16(bc8(F[i]), bc8(wreg[8 + i]), fa);
      __syncthreads();
      if (khalf) {
        float* rb = &redu[(wsub * 64 + lane) * 17];
#pragma unroll
        for (int g = 0; g < 4; ++g) rb[g] = fa[g];
      }
      __syncthreads();
      if (!khalf) {
        const float* rb = &redu[(wsub * 64 + lane) * 17];
        const int jf = j0f + rr;
        const bool first = fcDir ? (tf >= 256) : (tf <= 255);
        if (first) {
#pragma unroll
          for (int g = 0; g < 4; ++g) {
            const int b = wsub * 16 + qq * 4 + g;
            float v = (fa[g] + rb[g]) + bvFC;
            GSTORED(dout + (long)b * 262144 + (long)tf * 512 + jf, v);
          }
        } else {
          float pv[4];
#pragma unroll
          for (int g = 0; g < 4; ++g)
            GLOADD(pv[g], dout + (long)(wsub * 16 + qq * 4 + g) * 262144 + (long)tf * 512 + jf);
          VMWAIT0;
#pragma unroll
          for (int g = 0; g < 4; ++g) {
            float v = pv[g] + (fa[g] + rb[g]);
            GSTORED(dout + (long)(wsub * 16 + qq * 4 + g) * 262144 + (long)tf * 512 + jf, v);
          }
        }
      }
    }

    // ---------------- device barrier: parallel flags + replicated gen ----------------
    if (s < 513) {
      asm volatile("s_waitcnt vmcnt(0)" ::: "memory");   // drain this wave's sc1 stores
      __syncthreads();
      const unsigned gen = (unsigned)(s + 1);
      if (blk == 0) {
        if (tid == 0)
          __hip_atomic_store(flags, gen, __ATOMIC_RELAXED, __HIP_MEMORY_SCOPE_AGENT);
        if (tid < 256) {
          while (__hip_atomic_load(flags + tid * 16, __ATOMIC_RELAXED, __HIP_MEMORY_SCOPE_AGENT) < gen)
            __builtin_amdgcn_s_sleep(1);
        }
        __syncthreads();
        if (tid < 8)
          __hip_atomic_store(barGenA + tid * 16, gen, __ATOMIC_RELAXED, __HIP_MEMORY_SCOPE_AGENT);
      } else {
        if (tid == 0) {
          __hip_atomic_store(flags + blk * 16, gen, __ATOMIC_RELAXED, __HIP_MEMORY_SCOPE_AGENT);
          while (__hip_atomic_load(barGenA + (blk & 7) * 16, __ATOMIC_RELAXED, __HIP_MEMORY_SCOPE_AGENT) < gen)
            __builtin_amdgcn_s_sleep(1);
        }
        __syncthreads();
      }
    }
  }
}

extern "C" void kernel_launch(void* const* d_in, const int* in_sizes, int n_in,
                              void* d_out, int out_size, void* d_ws, size_t ws_size,
                              hipStream_t stream) {
  (void)in_sizes; (void)n_in; (void)out_size; (void)ws_size;
  char* ws = (char*)d_ws;
  const float* x = (const float*)d_in[0];
  __hip_bfloat16* wt = (__hip_bfloat16*)(ws + OFF_WT);

  // zero h state + barrier flags (graph replays re-run these)
  (void)hipMemsetAsync(ws + OFF_H16, 0, 1048576, stream);
  (void)hipMemsetAsync(ws + OFF_BAR, 0, 16896, stream);

  // transpose-cast weights: src [K][3072] -> dst [3072][K] (and fc [2048][512] -> [512][2048])
  dim3 tb(32, 8);
  transpose_cast<<<dim3(96, 16), tb, 0, stream>>>((const float*)d_in[1],  wt + E_FW_WXT0, 512,  3072);
  transpose_cast<<<dim3(96, 32), tb, 0, stream>>>((const float*)d_in[2],  wt + E_FW_WHT0, 1024, 3072);
  transpose_cast<<<dim3(96, 32), tb, 0, stream>>>((const float*)d_in[5],  wt + E_FW_WXT1, 1024, 3072);
  transpose_cast<<<dim3(96, 32), tb, 0, stream>>>((const float*)d_in[6],  wt + E_FW_WHT1, 1024, 3072);
  transpose_cast<<<dim3(96, 16), tb, 0, stream>>>((const float*)d_in[9],  wt + E_BW_WXT0, 512,  3072);
  transpose_cast<<<dim3(96, 32), tb, 0, stream>>>((const float*)d_in[10], wt + E_BW_WHT0, 1024, 3072);
  transpose_cast<<<dim3(96, 32), tb, 0, stream>>>((const float*)d_in[13], wt + E_BW_WXT1, 1024, 3072);
  transpose_cast<<<dim3(96, 32), tb, 0, stream>>>((const float*)d_in[14], wt + E_BW_WHT1, 1024, 3072);
  transpose_cast<<<dim3(16, 64), tb, 0, stream>>>((const float*)d_in[17], wt + E_FCWT,    2048, 512);

  const float* fwbx0 = (const float*)d_in[3];
  const float* fwbh0 = (const float*)d_in[4];
  const float* fwbx1 = (const float*)d_in[7];
  const float* fwbh1 = (const float*)d_in[8];
  const float* bwbx0 = (const float*)d_in[11];
  const float* bwbh0 = (const float*)d_in[12];
  const float* bwbx1 = (const float*)d_in[15];
  const float* bwbh1 = (const float*)d_in[16];
  const float* fcb   = (const float*)d_in[18];
  float* dop = (float*)d_out;

  static bool attrSet = false;
  if (!attrSet) {
    (void)hipFuncSetAttribute(reinterpret_cast<const void*>(bigru_persist),
                              hipFuncAttributeMaxDynamicSharedMemorySize, 131072);
    attrSet = true;
  }

  void* args[] = {&ws, &x, &fwbx0, &fwbh0, &fwbx1, &fwbh1,
                  &bwbx0, &bwbh0, &bwbx1, &bwbh1, &fcb, &dop};
  hipError_t e = hipLaunchCooperativeKernel(reinterpret_cast<const void*>(bigru_persist),
                                            dim3(256), dim3(512), args, 131072, stream);
  if (e != hipSuccess) {
    // fallback: plain launch (256 blocks on 256 CUs, 1 block/CU -> co-resident in practice)
    bigru_persist<<<dim3(256), dim3(512), 131072, stream>>>(
        ws, (const float*)x, fwbx0, fwbh0, fwbx1, fwbh1,
        bwbx0, bwbh0, bwbx1, bwbh1, fcb, dop);
  }
}